// Round 10
// baseline (183.965 us; speedup 1.0000x reference)
//
#include <hip/hip_runtime.h>

typedef float v2f __attribute__((ext_vector_type(2)));

#define NB 32
#define N0 20000
#define N1 10000
#define N2 10000
#define NF4_A 10000        // float4s per (b, side) beta_0 stream
#define NF4_E0 5000        // float4s of ext0 per b
#define NF4_E 10000        // float4s of ext0+ext1 per b
#define NCH 157            // ceil(10000/64): 64-float4 chunks per A stream
#define T_A 14             // A-role chunk stride (1792 A-blocks)
#define KC_A 8             // centers per A wave
#define KC_B 16            // centers per E block
#define NBINS 4096
#define NBLK 2048          // total blocks (256 E + 1792 A)
#define SENT 3.0e4f        // sentinel: per-term contribution ~ -1e-10

// R10 = R8 structure (best measured: hat 41us; 256 E + 1792 A x 256thr,
// 8 blocks/CU) + two additions:
//  (1) in-kernel tpl fold (R9-validated counter at out[4096] + threadfence
//      release/acquire; last-finishing block reduces) -> tpl dispatch gone.
//  (2) A-loop unroll x2 with 2-deep prefetch: two independent 8-center
//      rcp/fma chains in the scheduler window (the idle-cycle suspect is
//      dependency stalls around quarter-rate v_rcp_f32), half the loop
//      overhead. VGPR 32 -> ~48, still <= 64 for 8 waves/SIMD.
// R9 lesson: never drop blocks/CU below the 8-block cap (512x512 = 2
// blocks/CU regressed 41->47us).
__global__ __launch_bounds__(256, 8) void hat_kernel(
    const float* __restrict__ up0, const float* __restrict__ down0,
    const float* __restrict__ ext0, const float* __restrict__ ext1,
    const float* __restrict__ centers, const float* __restrict__ radius,
    float* __restrict__ out)
{
    const int tid  = threadIdx.x;
    const int lane = tid & 63;
    const int wave = tid >> 6;
    const float r  = fabsf(radius[0]);
    const int slot = blockIdx.x;

    __shared__ unsigned hist[NBINS];     // 16 KB (E-role)
    __shared__ float    red[4 * KC_B];   // E reduction / tpl scratch
    __shared__ unsigned lastFlag;

    if (slot < 256) {
        // ============ E-role: ext points, 1-D binned (R7/R8-validated) =====
        const int id   = slot;
        const int cc   = id & 3;         // 4 chunks of 16 centers
        const int side = (id >> 2) & 1;  // 0 = up (use y), 1 = down (use x)
        const int b    = id >> 3;
        const int cbase = cc * KC_B;

        for (int j = tid; j < NBINS; j += 256) hist[j] = 0;
        __syncthreads();

        // Build: one pass over ext0|ext1 as float4 (2 points each),
        // unconditional clamped pointer-select load, prefetched 1 ahead.
        const float4* e0 = (const float4*)(ext0 + (size_t)b * (N1*2));
        const float4* e1 = (const float4*)(ext1 + (size_t)b * (N2*2));
        #define EPTR(I) ((I) < NF4_E0 ? (e0 + (I)) : (e1 + ((I) - NF4_E0)))
        float4 q = *EPTR(tid);
        for (int i = tid; i < NF4_E; i += 256) {
            const float4 qc = q;
            q = *EPTR(min(i + 256, NF4_E - 1));
            const float vv0 = (side == 0) ? qc.y : qc.x;
            const float vv1 = (side == 0) ? qc.w : qc.z;
            int b0 = (int)(vv0 * (float)NBINS);
            int b1 = (int)(vv1 * (float)NBINS);
            b0 = min(max(b0, 0), NBINS - 1);
            b1 = min(max(b1, 0), NBINS - 1);
            atomicAdd(&hist[b0], 1u);
            atomicAdd(&hist[b1], 1u);
        }
        #undef EPTR
        __syncthreads();

        // centers: n_k(vv) = max(|1-(cx+cy)|, 2|vv - (1+cx-cy)/2|)
        float Ak[KC_B], mk[KC_B];
        #pragma unroll
        for (int k = 0; k < KC_B; ++k) {
            const float cx = centers[2*(cbase+k)];
            const float cy = centers[2*(cbase+k)+1];
            Ak[k] = fabsf(1.0f - (cx + cy));
            mk[k] = 0.5f * (1.0f + (cx - cy));
        }

        float part[KC_B];
        #pragma unroll
        for (int k = 0; k < KC_B; ++k) part[k] = 0.f;

        #pragma unroll
        for (int jj = 0; jj < NBINS/256; ++jj) {
            const int j = jj*256 + tid;
            const float cntf = (float)hist[j];
            const float vvj  = ((float)j + 0.5f) * (1.0f/(float)NBINS);
            #pragma unroll
            for (int k = 0; k < KC_B; ++k) {
                const float s  = vvj - mk[k];
                const float tt = fmaxf(Ak[k], 2.0f*fabsf(s));
                const float d1 = 1.0f + tt;
                const float rn = r - tt;
                const float d2 = 1.0f + fabsf(rn);
                const float rc = __builtin_amdgcn_rcpf(d1 * d2);
                part[k] = fmaf(cntf * (d2 - d1), rc, part[k]);
            }
        }

        // KC=16 butterfly (validated): center (lane>>2)&15 in part[0]
        {
            #pragma unroll
            for (int k = 0; k < 8; ++k) {
                const bool hi = lane & 32;
                const float send = hi ? part[k]   : part[k+8];
                const float keep = hi ? part[k+8] : part[k];
                part[k] = keep + __shfl_xor(send, 32, 64);
            }
            #pragma unroll
            for (int k = 0; k < 4; ++k) {
                const bool hi = lane & 16;
                const float send = hi ? part[k]   : part[k+4];
                const float keep = hi ? part[k+4] : part[k];
                part[k] = keep + __shfl_xor(send, 16, 64);
            }
            #pragma unroll
            for (int k = 0; k < 2; ++k) {
                const bool hi = lane & 8;
                const float send = hi ? part[k]   : part[k+2];
                const float keep = hi ? part[k+2] : part[k];
                part[k] = keep + __shfl_xor(send, 8, 64);
            }
            {
                const bool hi = lane & 4;
                const float send = hi ? part[0] : part[1];
                const float keep = hi ? part[1] : part[0];
                part[0] = keep + __shfl_xor(send, 4, 64);
            }
            part[0] += __shfl_xor(part[0], 2, 64);
            part[0] += __shfl_xor(part[0], 1, 64);
        }
        if ((lane & 3) == 0) red[wave * KC_B + (lane >> 2)] = part[0];
        __syncthreads();
        if (tid < KC_B) {
            const float s = red[tid] + red[KC_B + tid] + red[2*KC_B + tid] + red[3*KC_B + tid];
            atomicAdd(&out[b*128 + side*64 + cbase + tid], s);
        }
    } else {
        // ========= A-role: beta_0 points, exact 2-D, unroll x2 =========
        // aid = ((b*2 + side)*2 + half)*14 + tchunk   (1792 total)
        const int aid    = slot - 256;
        const int tchunk = aid % T_A;
        const int rest   = aid / T_A;
        const int half   = rest & 1;
        const int side   = (rest >> 1) & 1;
        const int b      = rest >> 2;
        const int cbase  = (half * 4 + wave) * KC_A;   // per-wave center group
        const int outBase = b*128 + side*64 + cbase;

        v2f nuc[KC_A], nvc[KC_A];
        #pragma unroll
        for (int k = 0; k < KC_A; ++k) {
            const float cx = centers[2*(cbase+k)];
            const float cy = centers[2*(cbase+k)+1];
            nuc[k] = (v2f){-(cx + cy), -(cx + cy)};
            nvc[k] = (v2f){-(cx - cy), -(cx - cy)};
        }

        const float4* base0 = (const float4*)((side == 0 ? up0 : down0) + (size_t)b * (N0*2));

        v2f acc[KC_A];
        #pragma unroll
        for (int k = 0; k < KC_A; ++k) acc[k] = (v2f){0.f, 0.f};
        const v2f one2 = (v2f){1.f, 1.f};

        #define ABODY(QC, TT) do {                                             \
            v2f u_ = (v2f){(QC).x + (QC).y, (QC).z + (QC).w};                  \
            v2f v_ = (v2f){(QC).x - (QC).y, (QC).z - (QC).w};                  \
            if ((TT)*64 + 63 >= NF4_A) {          /* wave-uniform: t==156 */   \
                const bool bad = ((TT)*64 + lane) >= NF4_A;                    \
                u_.x = bad ? SENT : u_.x;  u_.y = bad ? SENT : u_.y;           \
                v_.x = bad ? 0.f  : v_.x;  v_.y = bad ? 0.f  : v_.y;           \
            }                                                                  \
            _Pragma("unroll")                                                  \
            for (int k = 0; k < KC_A; ++k) {                                   \
                const v2f du = u_ + nuc[k];                                    \
                const v2f dv = v_ + nvc[k];                                    \
                const float tt0 = fmaxf(fabsf(du.x), fabsf(dv.x));             \
                const float tt1 = fmaxf(fabsf(du.y), fabsf(dv.y));             \
                const v2f tt = (v2f){tt0, tt1};                                \
                const v2f d1 = tt + one2;                                      \
                const float rn0 = r - tt0;                                     \
                const float rn1 = r - tt1;                                     \
                const v2f d2 = (v2f){1.f + fabsf(rn0), 1.f + fabsf(rn1)};      \
                const v2f dd  = d1 * d2;                                       \
                const v2f num = d2 - d1;                                       \
                const v2f rc  = (v2f){__builtin_amdgcn_rcpf(dd.x),             \
                                      __builtin_amdgcn_rcpf(dd.y)};            \
                acc[k] = __builtin_elementwise_fma(num, rc, acc[k]);           \
            }                                                                  \
        } while (0)

        // Unroll x2 over the t-loop, 2-deep clamped prefetch: two
        // independent 8-center chains in flight per iteration.
        float4 q0 = base0[min(tchunk*64 + lane, NF4_A - 1)];
        float4 q1 = base0[min((tchunk + T_A)*64 + lane, NF4_A - 1)];
        for (int t = tchunk; t < NCH; t += 2*T_A) {
            const float4 qa = q0, qb = q1;
            const int t2 = t + 2*T_A, t3 = t + 3*T_A;
            if (t2 < NCH) q0 = base0[min(t2*64 + lane, NF4_A - 1)];
            if (t3 < NCH) q1 = base0[min(t3*64 + lane, NF4_A - 1)];
            ABODY(qa, t);
            if (t + T_A < NCH) ABODY(qb, t + T_A);   // wave-uniform guard
        }
        #undef ABODY

        float a1[KC_A];
        #pragma unroll
        for (int k = 0; k < KC_A; ++k) a1[k] = acc[k].x + acc[k].y;

        // KC=8 butterfly (validated): value (lane>>3)&7 at (lane&7)==0
        {
            #pragma unroll
            for (int k = 0; k < 4; ++k) {
                const bool hi = lane & 32;
                const float send = hi ? a1[k]   : a1[k+4];
                const float keep = hi ? a1[k+4] : a1[k];
                a1[k] = keep + __shfl_xor(send, 32, 64);
            }
            #pragma unroll
            for (int k = 0; k < 2; ++k) {
                const bool hi = lane & 16;
                const float send = hi ? a1[k]   : a1[k+2];
                const float keep = hi ? a1[k+2] : a1[k];
                a1[k] = keep + __shfl_xor(send, 16, 64);
            }
            {
                const bool hi = lane & 8;
                const float send = hi ? a1[0] : a1[1];
                const float keep = hi ? a1[1] : a1[0];
                a1[0] = keep + __shfl_xor(send, 8, 64);
            }
            a1[0] += __shfl_xor(a1[0], 4, 64);
            a1[0] += __shfl_xor(a1[0], 2, 64);
            a1[0] += __shfl_xor(a1[0], 1, 64);
        }
        if ((lane & 7) == 0) {
            atomicAdd(&out[outBase + (lane >> 3)], a1[0]);
        }
    }

    // ===== epilogue: last-finishing block computes tpl in-kernel =====
    // out[4096] doubles as the block counter (zeroed by memset; only the
    // last block overwrites it with the final tpl value). R9-validated.
    __syncthreads();                 // drain this block's atomics (vmcnt(0))
    if (tid == 0) {
        __threadfence();             // release
        const unsigned old = atomicAdd((unsigned*)&out[NB*128], 1u);
        lastFlag = (old == NBLK - 1) ? 1u : 0u;
    }
    __syncthreads();
    if (lastFlag) {
        __threadfence();             // acquire: see all blocks' adds
        float s = 0.f;
        for (int i = tid; i < NB*64; i += 256) {
            const int b2 = i >> 6, k = i & 63;
            const float d = out[b2*128 + k] - out[b2*128 + 64 + k];
            s = fmaf(d, d, s);
        }
        #pragma unroll
        for (int o = 32; o > 0; o >>= 1) s += __shfl_xor(s, o, 64);
        if (lane == 0) red[wave] = s;
        __syncthreads();
        if (tid == 0) {
            out[NB*128] = -(red[0] + red[1] + red[2] + red[3]);
        }
    }
}

extern "C" void kernel_launch(void* const* d_in, const int* in_sizes, int n_in,
                              void* d_out, int out_size, void* d_ws, size_t ws_size,
                              hipStream_t stream) {
    const float* up0     = (const float*)d_in[0];
    const float* down0   = (const float*)d_in[1];
    const float* ext0    = (const float*)d_in[2];
    const float* ext1    = (const float*)d_in[3];
    const float* centers = (const float*)d_in[4];
    const float* radius  = (const float*)d_in[5];
    float* out = (float*)d_out;

    // zero accumulators AND the counter/tpl slot at out[4096]
    // (harness poisons d_out with 0xAA each iteration)
    hipMemsetAsync(out, 0, (NB * 128 + 1) * sizeof(float), stream);

    hat_kernel<<<dim3(NBLK), dim3(256), 0, stream>>>(
        up0, down0, ext0, ext1, centers, radius, out);
}

// Round 11
// 140.665 us; speedup vs baseline: 1.3078x; 1.3078x over previous
//
#include <hip/hip_runtime.h>

typedef float v2f __attribute__((ext_vector_type(2)));

#define NB 32
#define N0 20000
#define N1 10000
#define N2 10000
#define NF4_A 10000        // float4s per (b, side) beta_0 stream
#define NF4_E0 5000        // float4s of ext0 per b
#define NF4_E 10000        // float4s of ext0+ext1 per b
#define NCH 157            // ceil(10000/64): 64-float4 chunks per A stream
#define T_A 14             // A-role chunk stride (1792 A-blocks)
#define KC_A 8             // centers per A wave
#define KC_B 16            // centers per E block
#define NBINS 4096
#define NBLK 2048          // total blocks (256 E + 1792 A)
#define SENT 3.0e4f        // sentinel: per-term contribution ~ -1e-10

// R11 = R8 kernel VERBATIM (best measured hat: 41us; 256 E + 1792 A x
// 256thr, 8 blocks/CU, single-deep prefetch) + the R9-validated in-kernel
// tpl fold (counter at out[4096], threadfence release/acquire) -> the tpl
// dispatch is deleted. R10 lesson: unroll x2 under launch_bounds(256,8)'s
// 64-VGPR cap spilled to scratch (WRITE_SIZE 96KB -> 69MB, hat 41 -> 122us)
// -- do NOT widen the A-loop body. R9 lesson: keep 8 blocks/CU.
__global__ __launch_bounds__(256, 8) void hat_kernel(
    const float* __restrict__ up0, const float* __restrict__ down0,
    const float* __restrict__ ext0, const float* __restrict__ ext1,
    const float* __restrict__ centers, const float* __restrict__ radius,
    float* __restrict__ out)
{
    const int tid  = threadIdx.x;
    const int lane = tid & 63;
    const int wave = tid >> 6;
    const float r  = fabsf(radius[0]);
    const int slot = blockIdx.x;

    __shared__ unsigned hist[NBINS];     // 16 KB (E-role)
    __shared__ float    red[4 * KC_B];   // E reduction / tpl scratch
    __shared__ unsigned lastFlag;

    if (slot < 256) {
        // ============ E-role: ext points, 1-D binned (R7/R8-validated) =====
        const int id   = slot;
        const int cc   = id & 3;         // 4 chunks of 16 centers
        const int side = (id >> 2) & 1;  // 0 = up (use y), 1 = down (use x)
        const int b    = id >> 3;
        const int cbase = cc * KC_B;

        for (int j = tid; j < NBINS; j += 256) hist[j] = 0;
        __syncthreads();

        // Build: one pass over ext0|ext1 as float4 (2 points each),
        // unconditional clamped pointer-select load, prefetched 1 ahead.
        const float4* e0 = (const float4*)(ext0 + (size_t)b * (N1*2));
        const float4* e1 = (const float4*)(ext1 + (size_t)b * (N2*2));
        #define EPTR(I) ((I) < NF4_E0 ? (e0 + (I)) : (e1 + ((I) - NF4_E0)))
        float4 q = *EPTR(tid);
        for (int i = tid; i < NF4_E; i += 256) {
            const float4 qc = q;
            q = *EPTR(min(i + 256, NF4_E - 1));
            const float vv0 = (side == 0) ? qc.y : qc.x;
            const float vv1 = (side == 0) ? qc.w : qc.z;
            int b0 = (int)(vv0 * (float)NBINS);
            int b1 = (int)(vv1 * (float)NBINS);
            b0 = min(max(b0, 0), NBINS - 1);
            b1 = min(max(b1, 0), NBINS - 1);
            atomicAdd(&hist[b0], 1u);
            atomicAdd(&hist[b1], 1u);
        }
        #undef EPTR
        __syncthreads();

        // centers: n_k(vv) = max(|1-(cx+cy)|, 2|vv - (1+cx-cy)/2|)
        float Ak[KC_B], mk[KC_B];
        #pragma unroll
        for (int k = 0; k < KC_B; ++k) {
            const float cx = centers[2*(cbase+k)];
            const float cy = centers[2*(cbase+k)+1];
            Ak[k] = fabsf(1.0f - (cx + cy));
            mk[k] = 0.5f * (1.0f + (cx - cy));
        }

        float part[KC_B];
        #pragma unroll
        for (int k = 0; k < KC_B; ++k) part[k] = 0.f;

        #pragma unroll
        for (int jj = 0; jj < NBINS/256; ++jj) {
            const int j = jj*256 + tid;
            const float cntf = (float)hist[j];
            const float vvj  = ((float)j + 0.5f) * (1.0f/(float)NBINS);
            #pragma unroll
            for (int k = 0; k < KC_B; ++k) {
                const float s  = vvj - mk[k];
                const float tt = fmaxf(Ak[k], 2.0f*fabsf(s));
                const float d1 = 1.0f + tt;
                const float rn = r - tt;
                const float d2 = 1.0f + fabsf(rn);
                const float rc = __builtin_amdgcn_rcpf(d1 * d2);
                part[k] = fmaf(cntf * (d2 - d1), rc, part[k]);
            }
        }

        // KC=16 butterfly (validated): center (lane>>2)&15 in part[0]
        {
            #pragma unroll
            for (int k = 0; k < 8; ++k) {
                const bool hi = lane & 32;
                const float send = hi ? part[k]   : part[k+8];
                const float keep = hi ? part[k+8] : part[k];
                part[k] = keep + __shfl_xor(send, 32, 64);
            }
            #pragma unroll
            for (int k = 0; k < 4; ++k) {
                const bool hi = lane & 16;
                const float send = hi ? part[k]   : part[k+4];
                const float keep = hi ? part[k+4] : part[k];
                part[k] = keep + __shfl_xor(send, 16, 64);
            }
            #pragma unroll
            for (int k = 0; k < 2; ++k) {
                const bool hi = lane & 8;
                const float send = hi ? part[k]   : part[k+2];
                const float keep = hi ? part[k+2] : part[k];
                part[k] = keep + __shfl_xor(send, 8, 64);
            }
            {
                const bool hi = lane & 4;
                const float send = hi ? part[0] : part[1];
                const float keep = hi ? part[1] : part[0];
                part[0] = keep + __shfl_xor(send, 4, 64);
            }
            part[0] += __shfl_xor(part[0], 2, 64);
            part[0] += __shfl_xor(part[0], 1, 64);
        }
        if ((lane & 3) == 0) red[wave * KC_B + (lane >> 2)] = part[0];
        __syncthreads();
        if (tid < KC_B) {
            const float s = red[tid] + red[KC_B + tid] + red[2*KC_B + tid] + red[3*KC_B + tid];
            atomicAdd(&out[b*128 + side*64 + cbase + tid], s);
        }
    } else {
        // ========= A-role: beta_0 points, exact 2-D (R6/R8-validated) ======
        // aid = ((b*2 + side)*2 + half)*14 + tchunk   (1792 total)
        const int aid    = slot - 256;
        const int tchunk = aid % T_A;
        const int rest   = aid / T_A;
        const int half   = rest & 1;
        const int side   = (rest >> 1) & 1;
        const int b      = rest >> 2;
        const int cbase  = (half * 4 + wave) * KC_A;   // per-wave center group
        const int outBase = b*128 + side*64 + cbase;

        v2f nuc[KC_A], nvc[KC_A];
        #pragma unroll
        for (int k = 0; k < KC_A; ++k) {
            const float cx = centers[2*(cbase+k)];
            const float cy = centers[2*(cbase+k)+1];
            nuc[k] = (v2f){-(cx + cy), -(cx + cy)};
            nvc[k] = (v2f){-(cx - cy), -(cx - cy)};
        }

        const float4* base0 = (const float4*)((side == 0 ? up0 : down0) + (size_t)b * (N0*2));

        v2f acc[KC_A];
        #pragma unroll
        for (int k = 0; k < KC_A; ++k) acc[k] = (v2f){0.f, 0.f};
        const v2f one2 = (v2f){1.f, 1.f};

        // Unconditional clamped load, prefetched one iteration ahead.
        float4 q = base0[min(tchunk*64 + lane, NF4_A - 1)];
        for (int t = tchunk; t < NCH; t += T_A) {
            const float4 qc = q;
            const int tn = t + T_A;
            if (tn < NCH) {                       // wave-uniform
                q = base0[min(tn*64 + lane, NF4_A - 1)];
            }

            v2f u_ = (v2f){qc.x + qc.y, qc.z + qc.w};
            v2f v_ = (v2f){qc.x - qc.y, qc.z - qc.w};
            if (t*64 + 63 >= NF4_A) {             // wave-uniform: only t==156
                const bool bad = (t*64 + lane) >= NF4_A;
                u_.x = bad ? SENT : u_.x;  u_.y = bad ? SENT : u_.y;
                v_.x = bad ? 0.f  : v_.x;  v_.y = bad ? 0.f  : v_.y;
            }

            #pragma unroll
            for (int k = 0; k < KC_A; ++k) {
                const v2f du = u_ + nuc[k];
                const v2f dv = v_ + nvc[k];
                const float tt0 = fmaxf(fabsf(du.x), fabsf(dv.x));
                const float tt1 = fmaxf(fabsf(du.y), fabsf(dv.y));
                const v2f tt = (v2f){tt0, tt1};
                const v2f d1 = tt + one2;
                const float rn0 = r - tt0;
                const float rn1 = r - tt1;
                const v2f d2 = (v2f){1.f + fabsf(rn0), 1.f + fabsf(rn1)};
                const v2f dd  = d1 * d2;
                const v2f num = d2 - d1;
                const v2f rc  = (v2f){__builtin_amdgcn_rcpf(dd.x),
                                      __builtin_amdgcn_rcpf(dd.y)};
                acc[k] = __builtin_elementwise_fma(num, rc, acc[k]);
            }
        }

        float a1[KC_A];
        #pragma unroll
        for (int k = 0; k < KC_A; ++k) a1[k] = acc[k].x + acc[k].y;

        // KC=8 butterfly (validated): value (lane>>3)&7 at (lane&7)==0
        {
            #pragma unroll
            for (int k = 0; k < 4; ++k) {
                const bool hi = lane & 32;
                const float send = hi ? a1[k]   : a1[k+4];
                const float keep = hi ? a1[k+4] : a1[k];
                a1[k] = keep + __shfl_xor(send, 32, 64);
            }
            #pragma unroll
            for (int k = 0; k < 2; ++k) {
                const bool hi = lane & 16;
                const float send = hi ? a1[k]   : a1[k+2];
                const float keep = hi ? a1[k+2] : a1[k];
                a1[k] = keep + __shfl_xor(send, 16, 64);
            }
            {
                const bool hi = lane & 8;
                const float send = hi ? a1[0] : a1[1];
                const float keep = hi ? a1[1] : a1[0];
                a1[0] = keep + __shfl_xor(send, 8, 64);
            }
            a1[0] += __shfl_xor(a1[0], 4, 64);
            a1[0] += __shfl_xor(a1[0], 2, 64);
            a1[0] += __shfl_xor(a1[0], 1, 64);
        }
        if ((lane & 7) == 0) {
            atomicAdd(&out[outBase + (lane >> 3)], a1[0]);
        }
    }

    // ===== epilogue: last-finishing block computes tpl in-kernel =====
    // out[4096] doubles as the block counter (zeroed by memset; only the
    // last block overwrites it with the final tpl value). R9-validated;
    // R9/R10 confirmed fences+counter add no measurable traffic (WRITE_SIZE
    // stayed 96KB at 512 blocks).
    __syncthreads();                 // drain this block's atomics
    if (tid == 0) {
        __threadfence();             // release
        const unsigned old = atomicAdd((unsigned*)&out[NB*128], 1u);
        lastFlag = (old == NBLK - 1) ? 1u : 0u;
    }
    __syncthreads();
    if (lastFlag) {
        __threadfence();             // acquire: see all blocks' adds
        float s = 0.f;
        for (int i = tid; i < NB*64; i += 256) {
            const int b2 = i >> 6, k = i & 63;
            const float d = out[b2*128 + k] - out[b2*128 + 64 + k];
            s = fmaf(d, d, s);
        }
        #pragma unroll
        for (int o = 32; o > 0; o >>= 1) s += __shfl_xor(s, o, 64);
        if (lane == 0) red[wave] = s;
        __syncthreads();
        if (tid == 0) {
            out[NB*128] = -(red[0] + red[1] + red[2] + red[3]);
        }
    }
}

extern "C" void kernel_launch(void* const* d_in, const int* in_sizes, int n_in,
                              void* d_out, int out_size, void* d_ws, size_t ws_size,
                              hipStream_t stream) {
    const float* up0     = (const float*)d_in[0];
    const float* down0   = (const float*)d_in[1];
    const float* ext0    = (const float*)d_in[2];
    const float* ext1    = (const float*)d_in[3];
    const float* centers = (const float*)d_in[4];
    const float* radius  = (const float*)d_in[5];
    float* out = (float*)d_out;

    // zero accumulators AND the counter/tpl slot at out[4096]
    // (harness poisons d_out with 0xAA each iteration)
    hipMemsetAsync(out, 0, (NB * 128 + 1) * sizeof(float), stream);

    hat_kernel<<<dim3(NBLK), dim3(256), 0, stream>>>(
        up0, down0, ext0, ext1, centers, radius, out);
}

// Round 12
// 115.545 us; speedup vs baseline: 1.5922x; 1.2174x over previous
//
#include <hip/hip_runtime.h>

typedef float v2f __attribute__((ext_vector_type(2)));

#define NB 32
#define N0 20000
#define N1 10000
#define N2 10000
#define NF4_A 10000        // float4s per (b, side) beta_0 stream
#define NF4_E0 5000        // float4s of ext0 per b
#define NF4_E 10000        // float4s of ext0+ext1 per b
#define NCH 157            // ceil(10000/64): 64-float4 chunks per A stream
#define T_A 14             // A-role chunk stride (1792 A-blocks)
#define KC_A 8             // centers per A wave
#define KC_B 16            // centers per E block
#define NBINS 4096
#define NBLK 2048          // total blocks (256 E + 1792 A)
#define SENT 3.0e4f        // sentinel: per-term contribution ~ -1e-10

// R12 = R8 kernel VERBATIM (best hat: 41us) + FENCE-FREE in-kernel tpl fold.
// R11 lesson: __threadfence() per block = full agent fence = L2
// writeback+invalidate on non-coherent-L2 gfx950; 2048 of them evicted the
// shared A-streams (FETCH +7MB, WRITE +7.4MB, hat 41->88us). The fence is
// NOT needed: all cross-block data in out[] is written via device-scope
// atomicAdd (completes at the coherent point), and __syncthreads emits
// s_waitcnt vmcnt(0), so the counter bump strictly follows completion of
// this block's adds. The last block reads the accumulators with
// agent-scope atomic loads (coherent, bypasses stale L1/L2) -- no flush.
// R10 lesson: no unroll (spill at 64-VGPR cap). R9 lesson: 8 blocks/CU.
__global__ __launch_bounds__(256, 8) void hat_kernel(
    const float* __restrict__ up0, const float* __restrict__ down0,
    const float* __restrict__ ext0, const float* __restrict__ ext1,
    const float* __restrict__ centers, const float* __restrict__ radius,
    float* __restrict__ out)
{
    const int tid  = threadIdx.x;
    const int lane = tid & 63;
    const int wave = tid >> 6;
    const float r  = fabsf(radius[0]);
    const int slot = blockIdx.x;

    __shared__ unsigned hist[NBINS];     // 16 KB (E-role)
    __shared__ float    red[4 * KC_B];   // E reduction / tpl scratch
    __shared__ unsigned lastFlag;

    if (slot < 256) {
        // ============ E-role: ext points, 1-D binned (R7/R8-validated) =====
        const int id   = slot;
        const int cc   = id & 3;         // 4 chunks of 16 centers
        const int side = (id >> 2) & 1;  // 0 = up (use y), 1 = down (use x)
        const int b    = id >> 3;
        const int cbase = cc * KC_B;

        for (int j = tid; j < NBINS; j += 256) hist[j] = 0;
        __syncthreads();

        // Build: one pass over ext0|ext1 as float4 (2 points each),
        // unconditional clamped pointer-select load, prefetched 1 ahead.
        const float4* e0 = (const float4*)(ext0 + (size_t)b * (N1*2));
        const float4* e1 = (const float4*)(ext1 + (size_t)b * (N2*2));
        #define EPTR(I) ((I) < NF4_E0 ? (e0 + (I)) : (e1 + ((I) - NF4_E0)))
        float4 q = *EPTR(tid);
        for (int i = tid; i < NF4_E; i += 256) {
            const float4 qc = q;
            q = *EPTR(min(i + 256, NF4_E - 1));
            const float vv0 = (side == 0) ? qc.y : qc.x;
            const float vv1 = (side == 0) ? qc.w : qc.z;
            int b0 = (int)(vv0 * (float)NBINS);
            int b1 = (int)(vv1 * (float)NBINS);
            b0 = min(max(b0, 0), NBINS - 1);
            b1 = min(max(b1, 0), NBINS - 1);
            atomicAdd(&hist[b0], 1u);
            atomicAdd(&hist[b1], 1u);
        }
        #undef EPTR
        __syncthreads();

        // centers: n_k(vv) = max(|1-(cx+cy)|, 2|vv - (1+cx-cy)/2|)
        float Ak[KC_B], mk[KC_B];
        #pragma unroll
        for (int k = 0; k < KC_B; ++k) {
            const float cx = centers[2*(cbase+k)];
            const float cy = centers[2*(cbase+k)+1];
            Ak[k] = fabsf(1.0f - (cx + cy));
            mk[k] = 0.5f * (1.0f + (cx - cy));
        }

        float part[KC_B];
        #pragma unroll
        for (int k = 0; k < KC_B; ++k) part[k] = 0.f;

        #pragma unroll
        for (int jj = 0; jj < NBINS/256; ++jj) {
            const int j = jj*256 + tid;
            const float cntf = (float)hist[j];
            const float vvj  = ((float)j + 0.5f) * (1.0f/(float)NBINS);
            #pragma unroll
            for (int k = 0; k < KC_B; ++k) {
                const float s  = vvj - mk[k];
                const float tt = fmaxf(Ak[k], 2.0f*fabsf(s));
                const float d1 = 1.0f + tt;
                const float rn = r - tt;
                const float d2 = 1.0f + fabsf(rn);
                const float rc = __builtin_amdgcn_rcpf(d1 * d2);
                part[k] = fmaf(cntf * (d2 - d1), rc, part[k]);
            }
        }

        // KC=16 butterfly (validated): center (lane>>2)&15 in part[0]
        {
            #pragma unroll
            for (int k = 0; k < 8; ++k) {
                const bool hi = lane & 32;
                const float send = hi ? part[k]   : part[k+8];
                const float keep = hi ? part[k+8] : part[k];
                part[k] = keep + __shfl_xor(send, 32, 64);
            }
            #pragma unroll
            for (int k = 0; k < 4; ++k) {
                const bool hi = lane & 16;
                const float send = hi ? part[k]   : part[k+4];
                const float keep = hi ? part[k+4] : part[k];
                part[k] = keep + __shfl_xor(send, 16, 64);
            }
            #pragma unroll
            for (int k = 0; k < 2; ++k) {
                const bool hi = lane & 8;
                const float send = hi ? part[k]   : part[k+2];
                const float keep = hi ? part[k+2] : part[k];
                part[k] = keep + __shfl_xor(send, 8, 64);
            }
            {
                const bool hi = lane & 4;
                const float send = hi ? part[0] : part[1];
                const float keep = hi ? part[1] : part[0];
                part[0] = keep + __shfl_xor(send, 4, 64);
            }
            part[0] += __shfl_xor(part[0], 2, 64);
            part[0] += __shfl_xor(part[0], 1, 64);
        }
        if ((lane & 3) == 0) red[wave * KC_B + (lane >> 2)] = part[0];
        __syncthreads();
        if (tid < KC_B) {
            const float s = red[tid] + red[KC_B + tid] + red[2*KC_B + tid] + red[3*KC_B + tid];
            atomicAdd(&out[b*128 + side*64 + cbase + tid], s);
        }
    } else {
        // ========= A-role: beta_0 points, exact 2-D (R6/R8-validated) ======
        // aid = ((b*2 + side)*2 + half)*14 + tchunk   (1792 total)
        const int aid    = slot - 256;
        const int tchunk = aid % T_A;
        const int rest   = aid / T_A;
        const int half   = rest & 1;
        const int side   = (rest >> 1) & 1;
        const int b      = rest >> 2;
        const int cbase  = (half * 4 + wave) * KC_A;   // per-wave center group
        const int outBase = b*128 + side*64 + cbase;

        v2f nuc[KC_A], nvc[KC_A];
        #pragma unroll
        for (int k = 0; k < KC_A; ++k) {
            const float cx = centers[2*(cbase+k)];
            const float cy = centers[2*(cbase+k)+1];
            nuc[k] = (v2f){-(cx + cy), -(cx + cy)};
            nvc[k] = (v2f){-(cx - cy), -(cx - cy)};
        }

        const float4* base0 = (const float4*)((side == 0 ? up0 : down0) + (size_t)b * (N0*2));

        v2f acc[KC_A];
        #pragma unroll
        for (int k = 0; k < KC_A; ++k) acc[k] = (v2f){0.f, 0.f};
        const v2f one2 = (v2f){1.f, 1.f};

        // Unconditional clamped load, prefetched one iteration ahead.
        float4 q = base0[min(tchunk*64 + lane, NF4_A - 1)];
        for (int t = tchunk; t < NCH; t += T_A) {
            const float4 qc = q;
            const int tn = t + T_A;
            if (tn < NCH) {                       // wave-uniform
                q = base0[min(tn*64 + lane, NF4_A - 1)];
            }

            v2f u_ = (v2f){qc.x + qc.y, qc.z + qc.w};
            v2f v_ = (v2f){qc.x - qc.y, qc.z - qc.w};
            if (t*64 + 63 >= NF4_A) {             // wave-uniform: only t==156
                const bool bad = (t*64 + lane) >= NF4_A;
                u_.x = bad ? SENT : u_.x;  u_.y = bad ? SENT : u_.y;
                v_.x = bad ? 0.f  : v_.x;  v_.y = bad ? 0.f  : v_.y;
            }

            #pragma unroll
            for (int k = 0; k < KC_A; ++k) {
                const v2f du = u_ + nuc[k];
                const v2f dv = v_ + nvc[k];
                const float tt0 = fmaxf(fabsf(du.x), fabsf(dv.x));
                const float tt1 = fmaxf(fabsf(du.y), fabsf(dv.y));
                const v2f tt = (v2f){tt0, tt1};
                const v2f d1 = tt + one2;
                const float rn0 = r - tt0;
                const float rn1 = r - tt1;
                const v2f d2 = (v2f){1.f + fabsf(rn0), 1.f + fabsf(rn1)};
                const v2f dd  = d1 * d2;
                const v2f num = d2 - d1;
                const v2f rc  = (v2f){__builtin_amdgcn_rcpf(dd.x),
                                      __builtin_amdgcn_rcpf(dd.y)};
                acc[k] = __builtin_elementwise_fma(num, rc, acc[k]);
            }
        }

        float a1[KC_A];
        #pragma unroll
        for (int k = 0; k < KC_A; ++k) a1[k] = acc[k].x + acc[k].y;

        // KC=8 butterfly (validated): value (lane>>3)&7 at (lane&7)==0
        {
            #pragma unroll
            for (int k = 0; k < 4; ++k) {
                const bool hi = lane & 32;
                const float send = hi ? a1[k]   : a1[k+4];
                const float keep = hi ? a1[k+4] : a1[k];
                a1[k] = keep + __shfl_xor(send, 32, 64);
            }
            #pragma unroll
            for (int k = 0; k < 2; ++k) {
                const bool hi = lane & 16;
                const float send = hi ? a1[k]   : a1[k+2];
                const float keep = hi ? a1[k+2] : a1[k];
                a1[k] = keep + __shfl_xor(send, 16, 64);
            }
            {
                const bool hi = lane & 8;
                const float send = hi ? a1[0] : a1[1];
                const float keep = hi ? a1[1] : a1[0];
                a1[0] = keep + __shfl_xor(send, 8, 64);
            }
            a1[0] += __shfl_xor(a1[0], 4, 64);
            a1[0] += __shfl_xor(a1[0], 2, 64);
            a1[0] += __shfl_xor(a1[0], 1, 64);
        }
        if ((lane & 7) == 0) {
            atomicAdd(&out[outBase + (lane >> 3)], a1[0]);
        }
    }

    // ===== epilogue: fence-free last-block tpl fold =====
    // Ordering argument (no __threadfence anywhere):
    //  - all out[] accumulation is device-scope atomicAdd -> performed at
    //    the coherent point (cross-XCD safe, guide G12/m20);
    //  - __syncthreads emits s_waitcnt vmcnt(0), so every wave's atomics
    //    have COMPLETED before tid 0 bumps the counter;
    //  - counter hits NBLK only after all blocks' adds are complete;
    //  - last block reads accumulators with agent-scope atomic loads
    //    (coherent read path, immune to stale L1/L2) -- no L2 flush.
    __syncthreads();
    if (tid == 0) {
        const unsigned old = __hip_atomic_fetch_add(
            (unsigned*)&out[NB*128], 1u,
            __ATOMIC_RELAXED, __HIP_MEMORY_SCOPE_AGENT);
        lastFlag = (old == NBLK - 1) ? 1u : 0u;
    }
    __syncthreads();
    if (lastFlag) {
        float s = 0.f;
        for (int i = tid; i < NB*64; i += 256) {
            const int b2 = i >> 6, k = i & 63;
            const float vu = __hip_atomic_load(&out[b2*128 + k],
                __ATOMIC_RELAXED, __HIP_MEMORY_SCOPE_AGENT);
            const float vd = __hip_atomic_load(&out[b2*128 + 64 + k],
                __ATOMIC_RELAXED, __HIP_MEMORY_SCOPE_AGENT);
            const float d = vu - vd;
            s = fmaf(d, d, s);
        }
        #pragma unroll
        for (int o = 32; o > 0; o >>= 1) s += __shfl_xor(s, o, 64);
        if (lane == 0) red[wave] = s;
        __syncthreads();
        if (tid == 0) {
            out[NB*128] = -(red[0] + red[1] + red[2] + red[3]);
        }
    }
}

extern "C" void kernel_launch(void* const* d_in, const int* in_sizes, int n_in,
                              void* d_out, int out_size, void* d_ws, size_t ws_size,
                              hipStream_t stream) {
    const float* up0     = (const float*)d_in[0];
    const float* down0   = (const float*)d_in[1];
    const float* ext0    = (const float*)d_in[2];
    const float* ext1    = (const float*)d_in[3];
    const float* centers = (const float*)d_in[4];
    const float* radius  = (const float*)d_in[5];
    float* out = (float*)d_out;

    // zero accumulators AND the counter/tpl slot at out[4096]
    // (harness poisons d_out with 0xAA each iteration)
    hipMemsetAsync(out, 0, (NB * 128 + 1) * sizeof(float), stream);

    hat_kernel<<<dim3(NBLK), dim3(256), 0, stream>>>(
        up0, down0, ext0, ext1, centers, radius, out);
}